// Round 1
// baseline (2579.669 us; speedup 1.0000x reference)
//
#include <hip/hip_runtime.h>
#include <cstdint>
#include <cstddef>

#define D1 30
#define D2 28
#define C1 32
#define C2 64

__device__ __forceinline__ void fma4(float4& a, float s, const float4& w) {
    a.x = fmaf(s, w.x, a.x);
    a.y = fmaf(s, w.y, a.y);
    a.z = fmaf(s, w.z, a.z);
    a.w = fmaf(s, w.w, a.w);
}

// conv1 + bias + relu: x[b][32][32][32] (C_in=1) -> h1[bl][30][30][30][32] (NDHWC)
__global__ __launch_bounds__(256) void conv1_relu(
    const float* __restrict__ x, const float* __restrict__ w1,
    const float* __restrict__ b1, float* __restrict__ h1, int b0)
{
    const int z   = blockIdx.x;       // 0..29
    const int bl  = blockIdx.y;       // local batch index
    const int b   = b0 + bl;
    const int tid = threadIdx.x;
    const int c4    = tid & 7;        // channels c4*4 .. c4*4+3
    const int xslot = tid >> 3;       // 0..31

    // per-thread weights for 4 channels: 27 taps (held in VGPRs)
    float4 wr[27];
#pragma unroll
    for (int t = 0; t < 27; ++t)
        wr[t] = *reinterpret_cast<const float4*>(w1 + t * C1 + c4 * 4);
    const float4 bias = *reinterpret_cast<const float4*>(b1 + c4 * 4);

    const float* xb  = x  + (size_t)b * 32 * 32 * 32;
    float*       h1b = h1 + (size_t)bl * D1 * D1 * D1 * C1;

    for (int j = 0; j < 29; ++j) {
        const int s = xslot + 32 * j;
        if (s >= D1 * D1) break;           // 900 spatial positions per plane
        const int y  = s / D1;
        const int xx = s - y * D1;

        float4 acc = bias;
#pragma unroll
        for (int kd = 0; kd < 3; ++kd) {
#pragma unroll
            for (int kh = 0; kh < 3; ++kh) {
                const float* row = xb + ((size_t)(z + kd) * 32 + (y + kh)) * 32 + xx;
                const float a0 = row[0];
                const float a1 = row[1];
                const float a2 = row[2];
                const int t = (kd * 3 + kh) * 3;
                fma4(acc, a0, wr[t + 0]);
                fma4(acc, a1, wr[t + 1]);
                fma4(acc, a2, wr[t + 2]);
            }
        }
        acc.x = fmaxf(acc.x, 0.f);
        acc.y = fmaxf(acc.y, 0.f);
        acc.z = fmaxf(acc.z, 0.f);
        acc.w = fmaxf(acc.w, 0.f);

        *reinterpret_cast<float4*>(
            h1b + (((size_t)z * D1 + y) * D1 + xx) * C1 + c4 * 4) = acc;
    }
}

// conv2 + bias + relu + NCDHW transpose:
// h1[bl][30][30][30][32] -> out[b][64][28][28][28]
// block: (ytile 0..6, z 0..27, bl); 256 thr = 8 co-groups x 32 spatial slots
__global__ __launch_bounds__(256) void conv2_relu_t(
    const float* __restrict__ h1, const float* __restrict__ w2,
    const float* __restrict__ b2, float* __restrict__ out, int b0)
{
    // h1 tile [3][6][30][32ch], x-stride padded 32->36 words (bank phasing)
    __shared__ float lds[3 * 6 * 30 * 36];   // 77760 B

    const int ytile = blockIdx.x;   // 0..6
    const int z     = blockIdx.y;   // 0..27
    const int bl    = blockIdx.z;
    const int b     = b0 + bl;
    const int y0    = ytile * 4;
    const int tid   = threadIdx.x;

    // ---- stage h1[bl][z..z+2][y0..y0+5][0..29][0..31] into LDS ----
    const float* h1b = h1 + (size_t)bl * D1 * D1 * D1 * C1;
    for (int i = tid; i < 18 * 240; i += 256) {   // 18 rows x 240 float4
        const int p  = i / 240;
        const int r  = i - p * 240;
        const int zp = p / 6;
        const int yy = p - zp * 6;
        const int xx = r >> 3;
        const int c4 = r & 7;
        const float4 v = *reinterpret_cast<const float4*>(
            h1b + (((size_t)(z + zp) * D1 + (y0 + yy)) * D1 + xx) * C1 + c4 * 4);
        *reinterpret_cast<float4*>(
            &lds[((zp * 6 + yy) * 30 + xx) * 36 + c4 * 4]) = v;
    }
    __syncthreads();

    const int slot = tid & 31;      // spatial slot
    const int cg   = tid >> 5;      // 0..7 -> out channels cg*8 .. +7

    // per-j spatial positions (clamped so inactive threads read valid LDS)
    int rowbase[4];
#pragma unroll
    for (int j = 0; j < 4; ++j) {
        int s = slot + 32 * j;
        if (s > 111) s = 111;
        const int oy = s / D2;
        const int ox = s - oy * D2;
        rowbase[j] = (oy * 30 + ox) * 36;
    }

    const float4 bias0 = *reinterpret_cast<const float4*>(b2 + cg * 8);
    const float4 bias1 = *reinterpret_cast<const float4*>(b2 + cg * 8 + 4);
    float4 acc[4][2];
#pragma unroll
    for (int j = 0; j < 4; ++j) { acc[j][0] = bias0; acc[j][1] = bias1; }

    const float* wbase = w2 + cg * 8;

#pragma unroll 1
    for (int tap = 0; tap < 27; ++tap) {
        const int kd  = tap / 9;
        const int rem = tap - kd * 9;
        const int kh  = rem / 3;
        const int kw  = rem - kh * 3;
        const int tapoff = ((kd * 6 + kh) * 30 + kw) * 36;
        const float* wt = wbase + (size_t)tap * C1 * C2;
#pragma unroll 2
        for (int ci4 = 0; ci4 < 8; ++ci4) {
            const float* wp = wt + ci4 * 4 * C2;
            const float4 w00 = *reinterpret_cast<const float4*>(wp);
            const float4 w01 = *reinterpret_cast<const float4*>(wp + 4);
            const float4 w10 = *reinterpret_cast<const float4*>(wp + C2);
            const float4 w11 = *reinterpret_cast<const float4*>(wp + C2 + 4);
            const float4 w20 = *reinterpret_cast<const float4*>(wp + 2 * C2);
            const float4 w21 = *reinterpret_cast<const float4*>(wp + 2 * C2 + 4);
            const float4 w30 = *reinterpret_cast<const float4*>(wp + 3 * C2);
            const float4 w31 = *reinterpret_cast<const float4*>(wp + 3 * C2 + 4);
            const int abase = tapoff + ci4 * 4;
#pragma unroll
            for (int j = 0; j < 4; ++j) {
                const float4 a = *reinterpret_cast<const float4*>(&lds[rowbase[j] + abase]);
                fma4(acc[j][0], a.x, w00); fma4(acc[j][1], a.x, w01);
                fma4(acc[j][0], a.y, w10); fma4(acc[j][1], a.y, w11);
                fma4(acc[j][0], a.z, w20); fma4(acc[j][1], a.z, w21);
                fma4(acc[j][0], a.w, w30); fma4(acc[j][1], a.w, w31);
            }
        }
    }

    // ---- epilogue: relu + scatter to NCDHW ----
#pragma unroll
    for (int j = 0; j < 4; ++j) {
        const int s = slot + 32 * j;
        if (s >= 112) continue;
        const int oy = s / D2;
        const int ox = s - oy * D2;
        const int gy = y0 + oy;
        const float v[8] = { acc[j][0].x, acc[j][0].y, acc[j][0].z, acc[j][0].w,
                             acc[j][1].x, acc[j][1].y, acc[j][1].z, acc[j][1].w };
#pragma unroll
        for (int c = 0; c < 8; ++c) {
            const int co = cg * 8 + c;
            out[((((size_t)b * C2 + co) * D2 + z) * D2 + gy) * D2 + ox] =
                fmaxf(v[c], 0.f);
        }
    }
}

extern "C" void kernel_launch(void* const* d_in, const int* in_sizes, int n_in,
                              void* d_out, int out_size, void* d_ws, size_t ws_size,
                              hipStream_t stream)
{
    const float* x  = (const float*)d_in[0];
    const float* w1 = (const float*)d_in[1];
    const float* b1 = (const float*)d_in[2];
    const float* w2 = (const float*)d_in[3];
    const float* b2 = (const float*)d_in[4];
    float* out = (float*)d_out;
    float* h1  = (float*)d_ws;

    const size_t per_batch = (size_t)D1 * D1 * D1 * C1 * sizeof(float); // 3,456,000 B
    int bchunk = (int)(ws_size / per_batch);
    if (bchunk < 1)  bchunk = 1;
    if (bchunk > 64) bchunk = 64;

    for (int b0 = 0; b0 < 64; b0 += bchunk) {
        int bc = 64 - b0;
        if (bc > bchunk) bc = bchunk;
        conv1_relu<<<dim3(30, bc), 256, 0, stream>>>(x, w1, b1, h1, b0);
        conv2_relu_t<<<dim3(7, 28, bc), 256, 0, stream>>>(h1, w2, b2, out, b0);
    }
}

// Round 2
// 410.624 us; speedup vs baseline: 6.2823x; 6.2823x over previous
//
#include <hip/hip_runtime.h>
#include <cstdint>
#include <cstddef>

typedef __attribute__((ext_vector_type(8))) short bf16x8;
typedef __attribute__((ext_vector_type(4))) float f32x4;
typedef unsigned short u16;

#define H1_ZSTRIDE (30 * 32 * 32)      /* elems per z slice            */
#define H1_YSTRIDE (32 * 32)           /* elems per y row = 2048 B     */
#define H1_BATCH   (30 * 30 * 32 * 32) /* elems per batch = 1.84 MB    */
#define LDS_ROW_B  2112                /* 2048 + 64 pad: bank phasing  */
#define OUT_CSTR   21952               /* 28*28*28                     */

__device__ __forceinline__ u16 f2bf(float f) {
    union { float f; unsigned u; } v; v.f = f;
    unsigned r = v.u + 0x7FFF + ((v.u >> 16) & 1);   // RNE
    return (u16)(r >> 16);
}

// ---------------- conv1 + bias + relu -> bf16 h1 [bl][z][y][32x][32ci] ----
__global__ __launch_bounds__(256) void conv1_relu(
    const float* __restrict__ x, const float* __restrict__ w1,
    const float* __restrict__ b1, u16* __restrict__ h1, int b0)
{
    const int z   = blockIdx.x;        // 0..29
    const int bl  = blockIdx.y;
    const int b   = b0 + bl;
    const int tid = threadIdx.x;
    const int c4    = tid & 7;         // ci c4*4 .. +3
    const int xslot = tid >> 3;        // 0..31

    float4 wr[27];
#pragma unroll
    for (int t = 0; t < 27; ++t)
        wr[t] = *reinterpret_cast<const float4*>(w1 + t * 32 + c4 * 4);
    const float4 bias = *reinterpret_cast<const float4*>(b1 + c4 * 4);

    const float* xb  = x + (size_t)b * 32768;
    u16*         h1b = h1 + (size_t)bl * H1_BATCH;

    for (int j = 0; j < 29; ++j) {
        const int s = xslot + 32 * j;
        if (s >= 900) break;
        const int y  = s / 30;
        const int xx = s - y * 30;

        float4 acc = bias;
#pragma unroll
        for (int kd = 0; kd < 3; ++kd) {
#pragma unroll
            for (int kh = 0; kh < 3; ++kh) {
                const float* row = xb + ((size_t)(z + kd) * 32 + (y + kh)) * 32 + xx;
                const float a0 = row[0], a1 = row[1], a2 = row[2];
                const int t = (kd * 3 + kh) * 3;
                acc.x = fmaf(a0, wr[t].x, acc.x); acc.y = fmaf(a0, wr[t].y, acc.y);
                acc.z = fmaf(a0, wr[t].z, acc.z); acc.w = fmaf(a0, wr[t].w, acc.w);
                acc.x = fmaf(a1, wr[t+1].x, acc.x); acc.y = fmaf(a1, wr[t+1].y, acc.y);
                acc.z = fmaf(a1, wr[t+1].z, acc.z); acc.w = fmaf(a1, wr[t+1].w, acc.w);
                acc.x = fmaf(a2, wr[t+2].x, acc.x); acc.y = fmaf(a2, wr[t+2].y, acc.y);
                acc.z = fmaf(a2, wr[t+2].z, acc.z); acc.w = fmaf(a2, wr[t+2].w, acc.w);
            }
        }
        ushort4 st;
        st.x = f2bf(fmaxf(acc.x, 0.f));
        st.y = f2bf(fmaxf(acc.y, 0.f));
        st.z = f2bf(fmaxf(acc.z, 0.f));
        st.w = f2bf(fmaxf(acc.w, 0.f));
        *reinterpret_cast<ushort4*>(
            h1b + (size_t)z * H1_ZSTRIDE + (size_t)y * H1_YSTRIDE + xx * 32 + c4 * 4) = st;
    }
}

// ---------------- pack w2 fp32 DHWIO -> bf16 B-fragments ------------------
// wB[((tap*4 + nt)*64 + lane)*8 + j] = bf16(w2[tap][(lane>>4)*8 + j][nt*16 + (lane&15)])
__global__ __launch_bounds__(256) void pack_w2(
    const float* __restrict__ w2, u16* __restrict__ wB)
{
    const int tap = blockIdx.x;      // 0..26
    const int tid = threadIdx.x;
    const int nt = tid >> 6;
    const int l  = tid & 63;
    const int r = l & 15, q = l >> 4;
    u16* dst = wB + ((size_t)(tap * 4 + nt) * 64 + l) * 8;
#pragma unroll
    for (int j = 0; j < 8; ++j)
        dst[j] = f2bf(w2[(size_t)(tap * 32 + q * 8 + j) * 64 + nt * 16 + r]);
}

// ---------------- conv2 implicit-GEMM MFMA + bias + relu + NCDHW ----------
// block: 4 waves; wave w -> out z = z0+w, rows y0..y0+3, x 0..27 (7 m-tiles)
__global__ __launch_bounds__(256, 2) void conv2_mfma(
    const u16* __restrict__ h1, const u16* __restrict__ wB,
    const float* __restrict__ b2, float* __restrict__ out, int b0)
{
    __shared__ __align__(16) unsigned char smem[36 * LDS_ROW_B];  // 76032 B

    const int yg = blockIdx.x;      // 0..6
    const int zt = blockIdx.y;      // 0..6
    const int bl = blockIdx.z;
    const int b  = b0 + bl;
    const int y0 = yg * 4, z0 = zt * 4;
    const int tid = threadIdx.x;
    const int wv  = tid >> 6;       // wave id 0..3
    const int l   = tid & 63;
    const int r = l & 15, q = l >> 4;
    const int yl = r & 3, xg = r >> 2;

    // ---- stage h1[bl][z0..z0+5][y0..y0+5][0..31x][32ci] (36 rows x 2048B)
    {
        const char* gbase = (const char*)(h1 + (size_t)bl * H1_BATCH);
        for (int c = wv; c < 72; c += 4) {               // wave-uniform chunks
            const int rid = c >> 1, half = c & 1;
            const int zz = rid / 6, yy = rid - zz * 6;
            const char* src = gbase
                + ((size_t)(z0 + zz) * H1_ZSTRIDE + (size_t)(y0 + yy) * H1_YSTRIDE) * 2
                + half * 1024 + l * 16;
            unsigned char* dst = smem + rid * LDS_ROW_B + half * 1024;
            __builtin_amdgcn_global_load_lds(
                (const __attribute__((address_space(1))) void*)src,
                (__attribute__((address_space(3))) void*)dst, 16, 0, 0);
        }
    }
    __syncthreads();

    // ---- accumulators init with bias (C/D: col=lane&15, row=(lane>>4)*4+reg)
    f32x4 acc[7][4];
#pragma unroll
    for (int nt = 0; nt < 4; ++nt) {
        const float bv = b2[nt * 16 + r];
        const f32x4 bi = {bv, bv, bv, bv};
#pragma unroll
        for (int mt = 0; mt < 7; ++mt) acc[mt][nt] = bi;
    }

    // per-lane LDS A base: row (wv + kd)*6 + (yl + kh), x = mt*4 + xg + kw, ci-block q
    const int base_l = (wv * 6 + yl) * LDS_ROW_B + xg * 64 + q * 16;
    const u16* wBl = wB + (size_t)l * 8;

    bf16x8 Bc[4];
#pragma unroll
    for (int nt = 0; nt < 4; ++nt)
        Bc[nt] = *reinterpret_cast<const bf16x8*>(wBl + (size_t)nt * 512);

#pragma unroll 1
    for (int tap = 0; tap < 27; ++tap) {
        const int tnext = (tap < 26) ? tap + 1 : 0;
        bf16x8 Bn[4];
#pragma unroll
        for (int nt = 0; nt < 4; ++nt)
            Bn[nt] = *reinterpret_cast<const bf16x8*>(wBl + (size_t)(tnext * 4 + nt) * 512);

        const int kd = tap / 9;
        const int kh = (tap - kd * 9) / 3;
        const int kw = tap - kd * 9 - kh * 3;
        const unsigned char* ap = smem + base_l + (kd * 6 + kh) * LDS_ROW_B + kw * 64;

#pragma unroll
        for (int mt = 0; mt < 7; ++mt) {
            const bf16x8 a = *reinterpret_cast<const bf16x8*>(ap + mt * 256);
            acc[mt][0] = __builtin_amdgcn_mfma_f32_16x16x32_bf16(a, Bc[0], acc[mt][0], 0, 0, 0);
            acc[mt][1] = __builtin_amdgcn_mfma_f32_16x16x32_bf16(a, Bc[1], acc[mt][1], 0, 0, 0);
            acc[mt][2] = __builtin_amdgcn_mfma_f32_16x16x32_bf16(a, Bc[2], acc[mt][2], 0, 0, 0);
            acc[mt][3] = __builtin_amdgcn_mfma_f32_16x16x32_bf16(a, Bc[3], acc[mt][3], 0, 0, 0);
        }
#pragma unroll
        for (int nt = 0; nt < 4; ++nt) Bc[nt] = Bn[nt];
    }

    // ---- epilogue: relu + NCDHW store; lane: co = nt*16+r, x = mt*4+q, y = y0+reg
    const int z = z0 + wv;
    float* ob = out + (size_t)b * 64 * OUT_CSTR + (size_t)r * OUT_CSTR
                    + (size_t)z * 784 + (size_t)y0 * 28 + q;
#pragma unroll
    for (int mt = 0; mt < 7; ++mt) {
#pragma unroll
        for (int nt = 0; nt < 4; ++nt) {
            float* p = ob + (size_t)nt * 16 * OUT_CSTR + mt * 4;
            const f32x4 v = acc[mt][nt];
            p[0]  = fmaxf(v.x, 0.f);
            p[28] = fmaxf(v.y, 0.f);
            p[56] = fmaxf(v.z, 0.f);
            p[84] = fmaxf(v.w, 0.f);
        }
    }
}

extern "C" void kernel_launch(void* const* d_in, const int* in_sizes, int n_in,
                              void* d_out, int out_size, void* d_ws, size_t ws_size,
                              hipStream_t stream)
{
    const float* x  = (const float*)d_in[0];
    const float* w1 = (const float*)d_in[1];
    const float* b1 = (const float*)d_in[2];
    const float* w2 = (const float*)d_in[3];
    const float* b2 = (const float*)d_in[4];
    float* out = (float*)d_out;

    u16* wB = (u16*)d_ws;                               // 110,592 B packed weights
    u16* h1 = (u16*)((char*)d_ws + 131072);

    pack_w2<<<27, 256, 0, stream>>>(w2, wB);

    const size_t per_batch = (size_t)H1_BATCH * 2;      // 1,843,200 B
    size_t avail = ws_size > 131072 ? ws_size - 131072 : 0;
    int bchunk = (int)(avail / per_batch);
    if (bchunk < 1)  bchunk = 1;
    if (bchunk > 64) bchunk = 64;

    for (int b0 = 0; b0 < 64; b0 += bchunk) {
        int bc = 64 - b0;
        if (bc > bchunk) bc = bchunk;
        conv1_relu<<<dim3(30, bc), 256, 0, stream>>>(x, w1, b1, h1, b0);
        conv2_mfma<<<dim3(7, 7, bc), 256, 0, stream>>>(h1, wB, b2, out, b0);
    }
}

// Round 3
// 404.628 us; speedup vs baseline: 6.3754x; 1.0148x over previous
//
#include <hip/hip_runtime.h>
#include <cstdint>
#include <cstddef>

typedef __attribute__((ext_vector_type(8))) short bf16x8;
typedef __attribute__((ext_vector_type(4))) float f32x4;
typedef unsigned short u16;

#define H1_ZSTRIDE (30 * 32 * 32)      /* elems per z slice            */
#define H1_YSTRIDE (32 * 32)           /* elems per y row = 2048 B     */
#define H1_BATCH   (30 * 30 * 32 * 32) /* elems per batch = 1.84 MB    */
#define LDS_ROW_B  1920                /* x 0..29, 32ci bf16           */
#define LDS_B_OFF  (36 * LDS_ROW_B)    /* 69120: B double buffer       */
#define OUT_CSTR   21952               /* 28*28*28                     */

__device__ __forceinline__ u16 f2bf(float f) {
    union { float f; unsigned u; } v; v.f = f;
    unsigned r = v.u + 0x7FFF + ((v.u >> 16) & 1);   // RNE
    return (u16)(r >> 16);
}

__device__ __forceinline__ void fma4(float4& a, float s, const float4& w) {
    a.x = fmaf(s, w.x, a.x);
    a.y = fmaf(s, w.y, a.y);
    a.z = fmaf(s, w.z, a.z);
    a.w = fmaf(s, w.w, a.w);
}

// ---------------- conv1 + bias + relu -> bf16 h1 [bl][z][y][32x][32ci] ----
// weights in LDS (broadcast reads) -> low VGPR, high occupancy
__global__ __launch_bounds__(256) void conv1_relu(
    const float* __restrict__ x, const float* __restrict__ w1,
    const float* __restrict__ b1, u16* __restrict__ h1, int b0)
{
    __shared__ float wl[27 * 32 + 32];

    const int z   = blockIdx.x;        // 0..29
    const int bl  = blockIdx.y;
    const int b   = b0 + bl;
    const int tid = threadIdx.x;

    for (int i = tid; i < 27 * 32; i += 256) wl[i] = w1[i];
    if (tid < 32) wl[27 * 32 + tid] = b1[tid];
    __syncthreads();

    const int c4    = tid & 7;         // ci c4*4 .. +3
    const int xslot = tid >> 3;        // 0..31

    const float4 bias = *reinterpret_cast<const float4*>(&wl[27 * 32 + c4 * 4]);
    const float* xb  = x + (size_t)b * 32768;
    u16*         h1b = h1 + (size_t)bl * H1_BATCH;

    for (int j = 0; j < 29; ++j) {
        const int s = xslot + 32 * j;
        if (s >= 900) break;
        const int y  = s / 30;
        const int xx = s - y * 30;

        float4 acc = bias;
#pragma unroll
        for (int kd = 0; kd < 3; ++kd) {
#pragma unroll
            for (int kh = 0; kh < 3; ++kh) {
                const float* row = xb + ((size_t)(z + kd) * 32 + (y + kh)) * 32 + xx;
                const float a0 = row[0], a1 = row[1], a2 = row[2];
                const int t = (kd * 3 + kh) * 3;
                const float4 w0 = *reinterpret_cast<const float4*>(&wl[(t + 0) * 32 + c4 * 4]);
                const float4 w1v = *reinterpret_cast<const float4*>(&wl[(t + 1) * 32 + c4 * 4]);
                const float4 w2v = *reinterpret_cast<const float4*>(&wl[(t + 2) * 32 + c4 * 4]);
                fma4(acc, a0, w0);
                fma4(acc, a1, w1v);
                fma4(acc, a2, w2v);
            }
        }
        ushort4 st;
        st.x = f2bf(fmaxf(acc.x, 0.f));
        st.y = f2bf(fmaxf(acc.y, 0.f));
        st.z = f2bf(fmaxf(acc.z, 0.f));
        st.w = f2bf(fmaxf(acc.w, 0.f));
        *reinterpret_cast<ushort4*>(
            h1b + (size_t)z * H1_ZSTRIDE + (size_t)y * H1_YSTRIDE + xx * 32 + c4 * 4) = st;
    }
}

// ---------------- pack w2 fp32 DHWIO -> bf16 B-fragments ------------------
// wB[((tap*4 + nt)*64 + lane)*8 + j] = bf16(w2[tap][(lane>>4)*8 + j][nt*16 + (lane&15)])
__global__ __launch_bounds__(256) void pack_w2(
    const float* __restrict__ w2, u16* __restrict__ wB)
{
    const int tap = blockIdx.x;      // 0..26
    const int tid = threadIdx.x;
    const int nt = tid >> 6;
    const int l  = tid & 63;
    const int r = l & 15, q = l >> 4;
    u16* dst = wB + ((size_t)(tap * 4 + nt) * 64 + l) * 8;
#pragma unroll
    for (int j = 0; j < 8; ++j)
        dst[j] = f2bf(w2[(size_t)(tap * 32 + q * 8 + j) * 64 + nt * 16 + r]);
}

// ---------------- conv2 implicit-GEMM MFMA + bias + relu + NCDHW ----------
// block: 4 waves; wave w -> out z = z0+w, rows y0..y0+3, x 0..27 (7 m-tiles)
// A tile in LDS (36 rows x 1920 B); B per-tap double-buffered in LDS (2x4KB)
__global__ __launch_bounds__(256, 2) void conv2_mfma(
    const u16* __restrict__ h1, const u16* __restrict__ wB,
    const float* __restrict__ b2, float* __restrict__ out, int b0)
{
    __shared__ __align__(16) unsigned char smem[LDS_B_OFF + 8192];  // 77312 B

    const int yg = blockIdx.x;      // 0..6
    const int zt = blockIdx.y;      // 0..6
    const int bl = blockIdx.z;
    const int b  = b0 + bl;
    const int y0 = yg * 4, z0 = zt * 4;
    const int tid = threadIdx.x;
    const int wv  = tid >> 6;       // wave id 0..3
    const int l   = tid & 63;
    const int r = l & 15, q = l >> 4;
    const int yl = r & 3, xg = r >> 2;

    const char* wBb = (const char*)wB;

    // ---- stage A: h1[bl][z0..z0+5][y0..y0+5][x 0..29][32ci]  (36 x 1920 B)
    // two overlapped 1024-B chunks per row (offsets 0 and 896) -> no exec mask
    {
        const char* gbase = (const char*)(h1 + (size_t)bl * H1_BATCH);
        for (int c = wv; c < 72; c += 4) {               // wave-uniform chunks
            const int rid = c >> 1, half = c & 1;
            const int zz = rid / 6, yy = rid - zz * 6;
            const char* src = gbase
                + ((size_t)(z0 + zz) * H1_ZSTRIDE + (size_t)(y0 + yy) * H1_YSTRIDE) * 2
                + half * 896 + l * 16;
            unsigned char* dst = smem + rid * LDS_ROW_B + half * 896 + l * 16;
            __builtin_amdgcn_global_load_lds(
                (const __attribute__((address_space(1))) void*)src,
                (__attribute__((address_space(3))) void*)dst, 16, 0, 0);
        }
        // stage B for tap 0 into buf 0: 4 KB, one 1-KB chunk per wave
        const char* bsrc = wBb + wv * 1024 + l * 16;
        unsigned char* bdst = smem + LDS_B_OFF + wv * 1024 + l * 16;
        __builtin_amdgcn_global_load_lds(
            (const __attribute__((address_space(1))) void*)bsrc,
            (__attribute__((address_space(3))) void*)bdst, 16, 0, 0);
    }
    __syncthreads();

    // ---- accumulators init with bias (C/D: col=lane&15, row=(lane>>4)*4+reg)
    f32x4 acc[7][4];
#pragma unroll
    for (int nt = 0; nt < 4; ++nt) {
        const float bv = b2[nt * 16 + r];
        const f32x4 bi = {bv, bv, bv, bv};
#pragma unroll
        for (int mt = 0; mt < 7; ++mt) acc[mt][nt] = bi;
    }

    // per-lane LDS A base: row (wv + kd)*6 + (yl + kh), x = mt*4 + xg + kw, ci-block q
    const unsigned char* aBase = smem + (wv * 6 + yl) * LDS_ROW_B + xg * 64 + q * 16;

#pragma unroll 1
    for (int tap = 0; tap < 27; ++tap) {
        const int cur = tap & 1;

        // issue next tap's B stage (4 KB shared, 1 chunk per wave); lands
        // before the end-of-tap barrier (compiler drains vmcnt there)
        if (tap < 26) {
            const char* bsrc = wBb + (size_t)(tap + 1) * 4096 + wv * 1024 + l * 16;
            unsigned char* bdst = smem + LDS_B_OFF + (cur ^ 1) * 4096 + wv * 1024 + l * 16;
            __builtin_amdgcn_global_load_lds(
                (const __attribute__((address_space(1))) void*)bsrc,
                (__attribute__((address_space(3))) void*)bdst, 16, 0, 0);
        }

        const unsigned char* bp = smem + LDS_B_OFF + cur * 4096 + l * 16;
        bf16x8 B0 = *reinterpret_cast<const bf16x8*>(bp);
        bf16x8 B1 = *reinterpret_cast<const bf16x8*>(bp + 1024);
        bf16x8 B2 = *reinterpret_cast<const bf16x8*>(bp + 2048);
        bf16x8 B3 = *reinterpret_cast<const bf16x8*>(bp + 3072);

        const int kd = tap / 9;
        const int kh = (tap - kd * 9) / 3;
        const int kw = tap - kd * 9 - kh * 3;
        const unsigned char* ap = aBase + (kd * 6 + kh) * LDS_ROW_B + kw * 64;

#pragma unroll
        for (int mt = 0; mt < 7; ++mt) {
            const bf16x8 a = *reinterpret_cast<const bf16x8*>(ap + mt * 256);
            acc[mt][0] = __builtin_amdgcn_mfma_f32_16x16x32_bf16(a, B0, acc[mt][0], 0, 0, 0);
            acc[mt][1] = __builtin_amdgcn_mfma_f32_16x16x32_bf16(a, B1, acc[mt][1], 0, 0, 0);
            acc[mt][2] = __builtin_amdgcn_mfma_f32_16x16x32_bf16(a, B2, acc[mt][2], 0, 0, 0);
            acc[mt][3] = __builtin_amdgcn_mfma_f32_16x16x32_bf16(a, B3, acc[mt][3], 0, 0, 0);
        }
        __syncthreads();   // publishes next tap's B; drains vmcnt+lgkmcnt
    }

    // ---- epilogue: relu + NCDHW store; lane: co = nt*16+r, x = mt*4+q, y = y0+reg
    const int z = z0 + wv;
    float* ob = out + (size_t)b * 64 * OUT_CSTR + (size_t)r * OUT_CSTR
                    + (size_t)z * 784 + (size_t)y0 * 28 + q;
#pragma unroll
    for (int mt = 0; mt < 7; ++mt) {
#pragma unroll
        for (int nt = 0; nt < 4; ++nt) {
            float* p = ob + (size_t)nt * 16 * OUT_CSTR + mt * 4;
            const f32x4 v = acc[mt][nt];
            p[0]  = fmaxf(v.x, 0.f);
            p[28] = fmaxf(v.y, 0.f);
            p[56] = fmaxf(v.z, 0.f);
            p[84] = fmaxf(v.w, 0.f);
        }
    }
}

extern "C" void kernel_launch(void* const* d_in, const int* in_sizes, int n_in,
                              void* d_out, int out_size, void* d_ws, size_t ws_size,
                              hipStream_t stream)
{
    const float* x  = (const float*)d_in[0];
    const float* w1 = (const float*)d_in[1];
    const float* b1 = (const float*)d_in[2];
    const float* w2 = (const float*)d_in[3];
    const float* b2 = (const float*)d_in[4];
    float* out = (float*)d_out;

    u16* wB = (u16*)d_ws;                               // 110,592 B packed weights
    u16* h1 = (u16*)((char*)d_ws + 131072);

    pack_w2<<<27, 256, 0, stream>>>(w2, wB);

    const size_t per_batch = (size_t)H1_BATCH * 2;      // 1,843,200 B
    size_t avail = ws_size > 131072 ? ws_size - 131072 : 0;
    int bchunk = (int)(avail / per_batch);
    if (bchunk < 1)  bchunk = 1;
    if (bchunk > 64) bchunk = 64;

    for (int b0 = 0; b0 < 64; b0 += bchunk) {
        int bc = 64 - b0;
        if (bc > bchunk) bc = bchunk;
        conv1_relu<<<dim3(30, bc), 256, 0, stream>>>(x, w1, b1, h1, b0);
        conv2_mfma<<<dim3(7, 7, bc), 256, 0, stream>>>(h1, wB, b2, out, b0);
    }
}

// Round 4
// 394.065 us; speedup vs baseline: 6.5463x; 1.0268x over previous
//
#include <hip/hip_runtime.h>
#include <cstdint>
#include <cstddef>

typedef __attribute__((ext_vector_type(8))) short bf16x8;
typedef __attribute__((ext_vector_type(4))) float f32x4;
typedef __attribute__((ext_vector_type(4))) unsigned int u32x4;
typedef unsigned short u16;

#define H1_ROW_B   1920                 /* packed row: 30x * 32ci * 2B     */
#define H1_BATCH   (30 * 30 * 960)      /* elems per batch (864000)        */
#define LDS_ROW_B  1920
#define OUT_CSTR   21952                /* 28*28*28                        */

__device__ __forceinline__ u16 f2bf(float f) {
    union { float f; unsigned u; } v; v.f = f;
    unsigned r = v.u + 0x7FFF + ((v.u >> 16) & 1);   // RNE
    return (u16)(r >> 16);
}

__device__ __forceinline__ void fma4(float4& a, float s, const float4& w) {
    a.x = fmaf(s, w.x, a.x);
    a.y = fmaf(s, w.y, a.y);
    a.z = fmaf(s, w.z, a.z);
    a.w = fmaf(s, w.w, a.w);
}

// ---------------- conv1 + bias + relu -> bf16 h1 [bl][z][y][30x][32ci] ----
// grid (30 z, 5 ytiles, bc): 6 y-rows per block, 6-iter loop
__global__ __launch_bounds__(256) void conv1_relu(
    const float* __restrict__ x, const float* __restrict__ w1,
    const float* __restrict__ b1, u16* __restrict__ h1, int b0)
{
    __shared__ float wl[27 * 32 + 32];

    const int z   = blockIdx.x;        // 0..29
    const int yt  = blockIdx.y;        // 0..4
    const int bl  = blockIdx.z;
    const int b   = b0 + bl;
    const int tid = threadIdx.x;

    for (int i = tid; i < 27 * 32; i += 256) wl[i] = w1[i];
    if (tid < 32) wl[27 * 32 + tid] = b1[tid];
    __syncthreads();

    const int c4    = tid & 7;
    const int xslot = tid >> 3;

    const float4 bias = *reinterpret_cast<const float4*>(&wl[27 * 32 + c4 * 4]);
    const float* xb  = x + (size_t)b * 32768;
    u16*         h1b = h1 + (size_t)bl * H1_BATCH;

#pragma unroll 1
    for (int j = 0; j < 6; ++j) {
        const int s = xslot + 32 * j;       // 0..191 over 180 sites
        if (s >= 180) break;
        const int yy = s / 30;
        const int xx = s - yy * 30;
        const int y  = yt * 6 + yy;

        float4 acc = bias;
#pragma unroll
        for (int kd = 0; kd < 3; ++kd) {
#pragma unroll
            for (int kh = 0; kh < 3; ++kh) {
                const float* row = xb + ((size_t)(z + kd) * 32 + (y + kh)) * 32 + xx;
                const float a0 = row[0], a1 = row[1], a2 = row[2];
                const int t = (kd * 3 + kh) * 3;
                const float4 w0  = *reinterpret_cast<const float4*>(&wl[(t + 0) * 32 + c4 * 4]);
                const float4 w1v = *reinterpret_cast<const float4*>(&wl[(t + 1) * 32 + c4 * 4]);
                const float4 w2v = *reinterpret_cast<const float4*>(&wl[(t + 2) * 32 + c4 * 4]);
                fma4(acc, a0, w0);
                fma4(acc, a1, w1v);
                fma4(acc, a2, w2v);
            }
        }
        ushort4 st;
        st.x = f2bf(fmaxf(acc.x, 0.f));
        st.y = f2bf(fmaxf(acc.y, 0.f));
        st.z = f2bf(fmaxf(acc.z, 0.f));
        st.w = f2bf(fmaxf(acc.w, 0.f));
        *reinterpret_cast<ushort4*>(
            h1b + ((size_t)(z * 30 + y) * 30 + xx) * 32 + c4 * 4) = st;
    }
}

// ---------------- pack w2 fp32 DHWIO -> bf16 B-fragments ------------------
// wB[((tap*4 + nt)*64 + lane)*8 + j] = bf16(w2[tap][(lane>>4)*8 + j][nt*16 + (lane&15)])
__global__ __launch_bounds__(256) void pack_w2(
    const float* __restrict__ w2, u16* __restrict__ wB)
{
    const int tap = blockIdx.x;      // 0..26
    const int tid = threadIdx.x;
    const int nt = tid >> 6;
    const int l  = tid & 63;
    const int r = l & 15, q = l >> 4;
    u16* dst = wB + ((size_t)(tap * 4 + nt) * 64 + l) * 8;
#pragma unroll
    for (int j = 0; j < 8; ++j)
        dst[j] = f2bf(w2[(size_t)(tap * 32 + q * 8 + j) * 64 + nt * 16 + r]);
}

// ---------------- conv2 implicit-GEMM MFMA, barrier-free K-loop -----------
// 1-D grid 3136 = 49 tiles x 64 batches, XCD-swizzled.
// block: 4 waves; wave w -> out z = z0+w, rows y0..y0+3, x 0..27 (7 m-tiles)
// A tile in LDS (36 rows x 1920 B, staged once); B 2-tap-ahead in registers
// via inline-asm global_load_dwordx4 + counted s_waitcnt vmcnt(8).
__global__ __launch_bounds__(256, 2) void conv2_mfma(
    const u16* __restrict__ h1, const u16* __restrict__ wB,
    const float* __restrict__ b2, float* __restrict__ out, int b0)
{
    __shared__ __align__(16) unsigned char smem[36 * LDS_ROW_B];  // 69120 B

    // XCD-aware bijective swizzle: 3136 % 8 == 0
    const int lb = (blockIdx.x & 7) * 392 + (blockIdx.x >> 3);
    const int yg = lb % 7;
    const int zt = (lb / 7) % 7;
    const int bl = lb / 49;
    const int b  = b0 + bl;
    const int y0 = yg * 4, z0 = zt * 4;
    const int tid = threadIdx.x;
    const int wv  = tid >> 6;
    const int l   = tid & 63;
    const int r = l & 15, q = l >> 4;
    const int yl = r & 3, xg = r >> 2;

    // ---- B preload: taps 0,1 into register slots (drained by the barrier)
    const char* wBl = (const char*)wB + l * 16;
    u32x4 Bs[3][4];
#define B_LOAD(slot, t)                                                        \
    { const char* p_ = wBl + (size_t)(t) * 4096;                               \
      asm volatile("global_load_dwordx4 %0, %4, off\n\t"                       \
                   "global_load_dwordx4 %1, %4, off offset:1024\n\t"           \
                   "global_load_dwordx4 %2, %4, off offset:2048\n\t"           \
                   "global_load_dwordx4 %3, %4, off offset:3072"               \
                   : "=&v"(Bs[slot][0]), "=&v"(Bs[slot][1]),                   \
                     "=&v"(Bs[slot][2]), "=&v"(Bs[slot][3])                    \
                   : "v"(p_)); }
    B_LOAD(0, 0)
    B_LOAD(1, 1)

    // ---- stage A: h1[bl][z0..z0+5][y0..y0+5][x0..29][32ci]  (36 x 1920 B)
    {
        const char* gbase = (const char*)(h1 + (size_t)bl * H1_BATCH);
        for (int c = wv; c < 72; c += 4) {           // wave-uniform chunks
            const int rid = c >> 1, half = c & 1;
            const int zz = rid / 6, yy = rid - zz * 6;
            const char* src = gbase
                + (size_t)((z0 + zz) * 30 + (y0 + yy)) * H1_ROW_B
                + half * 896 + l * 16;
            unsigned char* dst = smem + rid * LDS_ROW_B + half * 896 + l * 16;
            __builtin_amdgcn_global_load_lds(
                (const __attribute__((address_space(1))) void*)src,
                (__attribute__((address_space(3))) void*)dst, 16, 0, 0);
        }
    }
    __syncthreads();   // drains staging + B(0),B(1)

    // ---- accumulators init with bias (C/D: col=lane&15, row=(lane>>4)*4+reg)
    f32x4 acc[7][4];
#pragma unroll
    for (int nt = 0; nt < 4; ++nt) {
        const float bv = b2[nt * 16 + r];
        const f32x4 bi = {bv, bv, bv, bv};
#pragma unroll
        for (int mt = 0; mt < 7; ++mt) acc[mt][nt] = bi;
    }

    const unsigned char* aBase = smem + (wv * 6 + yl) * LDS_ROW_B + xg * 64 + q * 16;

    // ---- barrier-free K-loop over 27 taps, fully unrolled ----
#pragma unroll
    for (int tap = 0; tap < 27; ++tap) {
        if (tap < 25) B_LOAD((tap + 2) % 3, tap + 2)

        // counted waits: outstanding after wait = loads of taps t+1, t+2
        if (tap < 25)       asm volatile("s_waitcnt vmcnt(8)" ::: "memory");
        else if (tap == 25) asm volatile("s_waitcnt vmcnt(4)" ::: "memory");
        else                asm volatile("s_waitcnt vmcnt(0)" ::: "memory");

        const int s = tap % 3;
        // tie B values to the post-wait point (rule #18: data-dep fence)
        asm volatile("" : "+v"(Bs[s][0]), "+v"(Bs[s][1]),
                          "+v"(Bs[s][2]), "+v"(Bs[s][3]));
        const bf16x8 B0 = __builtin_bit_cast(bf16x8, Bs[s][0]);
        const bf16x8 B1 = __builtin_bit_cast(bf16x8, Bs[s][1]);
        const bf16x8 B2 = __builtin_bit_cast(bf16x8, Bs[s][2]);
        const bf16x8 B3 = __builtin_bit_cast(bf16x8, Bs[s][3]);

        const int kd = tap / 9;
        const int kh = (tap - kd * 9) / 3;
        const int kw = tap - kd * 9 - kh * 3;
        const unsigned char* ap = aBase + (kd * 6 + kh) * LDS_ROW_B + kw * 64;

        __builtin_amdgcn_s_setprio(1);
#pragma unroll
        for (int mt = 0; mt < 7; ++mt) {
            const bf16x8 a = *reinterpret_cast<const bf16x8*>(ap + mt * 256);
            acc[mt][0] = __builtin_amdgcn_mfma_f32_16x16x32_bf16(a, B0, acc[mt][0], 0, 0, 0);
            acc[mt][1] = __builtin_amdgcn_mfma_f32_16x16x32_bf16(a, B1, acc[mt][1], 0, 0, 0);
            acc[mt][2] = __builtin_amdgcn_mfma_f32_16x16x32_bf16(a, B2, acc[mt][2], 0, 0, 0);
            acc[mt][3] = __builtin_amdgcn_mfma_f32_16x16x32_bf16(a, B3, acc[mt][3], 0, 0, 0);
        }
        __builtin_amdgcn_s_setprio(0);
    }
#undef B_LOAD

    // ---- epilogue: relu + NCDHW store; lane: co = nt*16+r, x = mt*4+q, y = y0+reg
    const int z = z0 + wv;
    float* ob = out + (size_t)b * 64 * OUT_CSTR + (size_t)r * OUT_CSTR
                    + (size_t)z * 784 + (size_t)y0 * 28 + q;
#pragma unroll
    for (int mt = 0; mt < 7; ++mt) {
#pragma unroll
        for (int nt = 0; nt < 4; ++nt) {
            float* p = ob + (size_t)nt * 16 * OUT_CSTR + mt * 4;
            const f32x4 v = acc[mt][nt];
            p[0]  = fmaxf(v.x, 0.f);
            p[28] = fmaxf(v.y, 0.f);
            p[56] = fmaxf(v.z, 0.f);
            p[84] = fmaxf(v.w, 0.f);
        }
    }
}

extern "C" void kernel_launch(void* const* d_in, const int* in_sizes, int n_in,
                              void* d_out, int out_size, void* d_ws, size_t ws_size,
                              hipStream_t stream)
{
    const float* x  = (const float*)d_in[0];
    const float* w1 = (const float*)d_in[1];
    const float* b1 = (const float*)d_in[2];
    const float* w2 = (const float*)d_in[3];
    const float* b2 = (const float*)d_in[4];
    float* out = (float*)d_out;

    u16* wB = (u16*)d_ws;                               // 110,592 B packed weights
    u16* h1 = (u16*)((char*)d_ws + 131072);

    pack_w2<<<27, 256, 0, stream>>>(w2, wB);

    const size_t per_batch = (size_t)H1_BATCH * 2;      // 1,728,000 B
    size_t avail = ws_size > 131072 ? ws_size - 131072 : 0;
    int bchunk = (int)(avail / per_batch);
    if (bchunk < 1)  bchunk = 1;
    if (bchunk > 64) bchunk = 64;

    for (int b0 = 0; b0 < 64; b0 += bchunk) {
        int bc = 64 - b0;
        if (bc > bchunk) bc = bchunk;
        conv1_relu<<<dim3(30, 5, bc), 256, 0, stream>>>(x, w1, b1, h1, b0);
        if (bc == 64) {
            conv2_mfma<<<dim3(3136), 256, 0, stream>>>(h1, wB, b2, out, b0);
        } else {
            // non-swizzled fallback path for partial chunks: launch per batch
            for (int i = 0; i < bc; ++i)
                conv2_mfma<<<dim3(49), 256, 0, stream>>>(
                    h1 + (size_t)i * H1_BATCH, wB, b2,
                    out + 0, b0 + i - 0);   // bl decoded from grid: lb/49==0 -> bl=0
        }
    }
}

// Round 6
// 359.426 us; speedup vs baseline: 7.1772x; 1.0964x over previous
//
#include <hip/hip_runtime.h>
#include <cstdint>
#include <cstddef>

typedef __attribute__((ext_vector_type(8))) short bf16x8;
typedef __attribute__((ext_vector_type(4))) float f32x4;
typedef __attribute__((ext_vector_type(4))) unsigned int u32x4;
typedef unsigned short u16;

#define H1_ROW_B   1920                 /* packed row: 30x * 32ci * 2B     */
#define H1_BATCH   (30 * 30 * 960)      /* elems per batch (864000)        */
#define LDS_STRIDE 1184                 /* 1152 + 32: bank phasing         */
#define OUT_CSTR   21952                /* 28*28*28                        */

__device__ __forceinline__ u16 f2bf(float f) {
    union { float f; unsigned u; } v; v.f = f;
    unsigned r = v.u + 0x7FFF + ((v.u >> 16) & 1);   // RNE
    return (u16)(r >> 16);
}

__device__ __forceinline__ void fma4(float4& a, float s, const float4& w) {
    a.x = fmaf(s, w.x, a.x);
    a.y = fmaf(s, w.y, a.y);
    a.z = fmaf(s, w.z, a.z);
    a.w = fmaf(s, w.w, a.w);
}

// ---------------- conv1 + bias + relu -> bf16 h1 [bl][z][y][30x][32ci] ----
__global__ __launch_bounds__(256) void conv1_relu(
    const float* __restrict__ x, const float* __restrict__ w1,
    const float* __restrict__ b1, u16* __restrict__ h1, int b0)
{
    __shared__ float wl[27 * 32 + 32];

    const int z   = blockIdx.x;        // 0..29
    const int yt  = blockIdx.y;        // 0..4
    const int bl  = blockIdx.z;
    const int b   = b0 + bl;
    const int tid = threadIdx.x;

    for (int i = tid; i < 27 * 32; i += 256) wl[i] = w1[i];
    if (tid < 32) wl[27 * 32 + tid] = b1[tid];
    __syncthreads();

    const int c4    = tid & 7;
    const int xslot = tid >> 3;

    const float4 bias = *reinterpret_cast<const float4*>(&wl[27 * 32 + c4 * 4]);
    const float* xb  = x + (size_t)b * 32768;
    u16*         h1b = h1 + (size_t)bl * H1_BATCH;

#pragma unroll 1
    for (int j = 0; j < 6; ++j) {
        const int s = xslot + 32 * j;       // over 180 sites
        if (s >= 180) break;
        const int yy = s / 30;
        const int xx = s - yy * 30;
        const int y  = yt * 6 + yy;

        float4 acc = bias;
#pragma unroll
        for (int kd = 0; kd < 3; ++kd) {
#pragma unroll
            for (int kh = 0; kh < 3; ++kh) {
                const float* row = xb + ((size_t)(z + kd) * 32 + (y + kh)) * 32 + xx;
                const float a0 = row[0], a1 = row[1], a2 = row[2];
                const int t = (kd * 3 + kh) * 3;
                const float4 w0  = *reinterpret_cast<const float4*>(&wl[(t + 0) * 32 + c4 * 4]);
                const float4 w1v = *reinterpret_cast<const float4*>(&wl[(t + 1) * 32 + c4 * 4]);
                const float4 w2v = *reinterpret_cast<const float4*>(&wl[(t + 2) * 32 + c4 * 4]);
                fma4(acc, a0, w0);
                fma4(acc, a1, w1v);
                fma4(acc, a2, w2v);
            }
        }
        ushort4 st;
        st.x = f2bf(fmaxf(acc.x, 0.f));
        st.y = f2bf(fmaxf(acc.y, 0.f));
        st.z = f2bf(fmaxf(acc.z, 0.f));
        st.w = f2bf(fmaxf(acc.w, 0.f));
        *reinterpret_cast<ushort4*>(
            h1b + ((size_t)(z * 30 + y) * 30 + xx) * 32 + c4 * 4) = st;
    }
}

// ---------------- pack w2 fp32 DHWIO -> bf16 B-fragments ------------------
// wB[((tap*4 + nt)*64 + lane)*8 + j] = bf16(w2[tap][(lane>>4)*8 + j][nt*16 + (lane&15)])
__global__ __launch_bounds__(256) void pack_w2(
    const float* __restrict__ w2, u16* __restrict__ wB)
{
    const int tap = blockIdx.x;      // 0..26
    const int tid = threadIdx.x;
    const int nt = tid >> 6;
    const int l  = tid & 63;
    const int r = l & 15, q = l >> 4;
    u16* dst = wB + ((size_t)(tap * 4 + nt) * 64 + l) * 8;
#pragma unroll
    for (int j = 0; j < 8; ++j)
        dst[j] = f2bf(w2[(size_t)(tap * 32 + q * 8 + j) * 64 + nt * 16 + r]);
}

// ---------------- conv2 implicit-GEMM MFMA, x-split tiles -----------------
// Grid 98*bc blocks (XCD-swizzled when %8==0). Per batch: 98 = 7yg*7zt*2xh.
// Block: 4 waves; wave wv -> z=z0+wv, y0..y0+3.
//   xh=0: out x 0..15 (4 m-tiles, XIN=0);  xh=1: out x 16..27 (3, XIN=12).
// A in LDS: 36 rows x 1152 B (18 x-pos), stride 1184 (bank phasing).
// B 1-tap-ahead in regs via inline-asm global_load_dwordx4 + vmcnt(4).
// m-tile site map: y = lane>>2 of r, x = (r&3)+mt*4 -> float4 x-contig stores.
template<int NMT, int XIN, int XOUT>
__device__ __forceinline__ void conv2_body(
    const unsigned char* smem, const char* wBl,
    const float* __restrict__ b2, float* __restrict__ out,
    int b, int y0, int z0, int wv, int l)
{
    const int r = l & 15, q = l >> 4;
    const int yl = r >> 2, xg = r & 3;

    f32x4 acc[NMT][4];
#pragma unroll
    for (int nt = 0; nt < 4; ++nt) {
        const float bv = b2[nt * 16 + r];
        const f32x4 bi = {bv, bv, bv, bv};
#pragma unroll
        for (int mt = 0; mt < NMT; ++mt) acc[mt][nt] = bi;
    }

    // per-lane A base; per tap add ((kd*6+kh)*LDS_STRIDE + kw*64) [const]
    const unsigned char* aBase =
        smem + (wv * 6 + yl) * LDS_STRIDE + (XOUT - XIN + xg) * 64 + q * 16;

    u32x4 Bs[2][4];
#define B_LOAD(slot, t)                                                        \
    { const char* p_ = wBl + (size_t)(t) * 4096;                               \
      asm volatile("global_load_dwordx4 %0, %4, off\n\t"                       \
                   "global_load_dwordx4 %1, %4, off offset:1024\n\t"           \
                   "global_load_dwordx4 %2, %4, off offset:2048\n\t"           \
                   "global_load_dwordx4 %3, %4, off offset:3072"               \
                   : "=&v"(Bs[slot][0]), "=&v"(Bs[slot][1]),                   \
                     "=&v"(Bs[slot][2]), "=&v"(Bs[slot][3])                    \
                   : "v"(p_)); }

    // tap-0 B load (staging loads already drained by caller's barrier, so
    // vmcnt counts below are exact: only our B loads are outstanding)
    B_LOAD(0, 0)

#pragma unroll
    for (int tap = 0; tap < 27; ++tap) {
        if (tap < 26) B_LOAD((tap + 1) & 1, tap + 1)

        // after wait: only tap t+1's 4 loads may remain in flight
        if (tap < 26) asm volatile("s_waitcnt vmcnt(4)");
        else          asm volatile("s_waitcnt vmcnt(0)");

        const int s = tap & 1;
        asm volatile("" : "+v"(Bs[s][0]), "+v"(Bs[s][1]),
                          "+v"(Bs[s][2]), "+v"(Bs[s][3]));
        const bf16x8 B0 = __builtin_bit_cast(bf16x8, Bs[s][0]);
        const bf16x8 B1 = __builtin_bit_cast(bf16x8, Bs[s][1]);
        const bf16x8 B2 = __builtin_bit_cast(bf16x8, Bs[s][2]);
        const bf16x8 B3 = __builtin_bit_cast(bf16x8, Bs[s][3]);

        const int kd = tap / 9;
        const int kh = (tap - kd * 9) / 3;
        const int kw = tap - kd * 9 - kh * 3;
        const unsigned char* ap = aBase + (kd * 6 + kh) * LDS_STRIDE + kw * 64;

        __builtin_amdgcn_s_setprio(1);
#pragma unroll
        for (int mt = 0; mt < NMT; ++mt) {
            const bf16x8 a = *reinterpret_cast<const bf16x8*>(ap + mt * 256);
            acc[mt][0] = __builtin_amdgcn_mfma_f32_16x16x32_bf16(a, B0, acc[mt][0], 0, 0, 0);
            acc[mt][1] = __builtin_amdgcn_mfma_f32_16x16x32_bf16(a, B1, acc[mt][1], 0, 0, 0);
            acc[mt][2] = __builtin_amdgcn_mfma_f32_16x16x32_bf16(a, B2, acc[mt][2], 0, 0, 0);
            acc[mt][3] = __builtin_amdgcn_mfma_f32_16x16x32_bf16(a, B3, acc[mt][3], 0, 0, 0);
        }
        __builtin_amdgcn_s_setprio(0);
    }
#undef B_LOAD

    // epilogue: lane (r,q): co = nt*16+r, y = y0+q, x = XOUT+mt*4 (+j contig)
    const int z = z0 + wv;
    float* ob = out + ((size_t)b * 64 + r) * OUT_CSTR
                    + (size_t)z * 784 + (size_t)(y0 + q) * 28 + XOUT;
#pragma unroll
    for (int mt = 0; mt < NMT; ++mt) {
#pragma unroll
        for (int nt = 0; nt < 4; ++nt) {
            const f32x4 v = acc[mt][nt];
            float4 st;
            st.x = fmaxf(v.x, 0.f);
            st.y = fmaxf(v.y, 0.f);
            st.z = fmaxf(v.z, 0.f);
            st.w = fmaxf(v.w, 0.f);
            *reinterpret_cast<float4*>(ob + (size_t)nt * 16 * OUT_CSTR + mt * 4) = st;
        }
    }
}

__global__ __launch_bounds__(256, 3) void conv2_mfma(
    const u16* __restrict__ h1, const u16* __restrict__ wB,
    const float* __restrict__ b2, float* __restrict__ out, int b0)
{
    __shared__ __align__(16) unsigned char smem[36 * LDS_STRIDE];  // 42624 B

    const int g   = gridDim.x;
    const int bid = blockIdx.x;
    const int lb  = (g % 8 == 0) ? ((bid & 7) * (g >> 3) + (bid >> 3)) : bid;

    const int t   = lb % 98;
    const int bl  = lb / 98;
    const int xh  = t / 49;
    const int u   = t % 49;
    const int yg  = u % 7;
    const int zt  = u / 7;

    const int b  = b0 + bl;
    const int y0 = yg * 4, z0 = zt * 4;
    const int tid = threadIdx.x;
    const int wv  = tid >> 6;
    const int l   = tid & 63;

    const char* wBl = (const char*)wB + l * 16;

    // ---- stage A: 36 rows x 1152 B from x-offset XIN, stride 1184 ----
    const int xin = xh ? 12 : 0;
    {
        const char* gbase = (const char*)(h1 + (size_t)bl * H1_BATCH) + xin * 64;
        for (int c = wv; c < 72; c += 4) {           // wave-uniform chunks
            const int rid = c >> 1, half = c & 1;    // two overlapped 1KB chunks
            const int zz = rid / 6, yy = rid - zz * 6;
            const char* src = gbase
                + (size_t)((z0 + zz) * 30 + (y0 + yy)) * H1_ROW_B
                + half * 128 + l * 16;
            unsigned char* dst = smem + rid * LDS_STRIDE + half * 128 + l * 16;
            __builtin_amdgcn_global_load_lds(
                (const __attribute__((address_space(1))) void*)src,
                (__attribute__((address_space(3))) void*)dst, 16, 0, 0);
        }
    }
    __syncthreads();   // drains staging (vmcnt(0)) + publishes LDS

    if (xh == 0)
        conv2_body<4, 0, 0>(smem, wBl, b2, out, b, y0, z0, wv, l);
    else
        conv2_body<3, 12, 16>(smem, wBl, b2, out, b, y0, z0, wv, l);
}

extern "C" void kernel_launch(void* const* d_in, const int* in_sizes, int n_in,
                              void* d_out, int out_size, void* d_ws, size_t ws_size,
                              hipStream_t stream)
{
    const float* x  = (const float*)d_in[0];
    const float* w1 = (const float*)d_in[1];
    const float* b1 = (const float*)d_in[2];
    const float* w2 = (const float*)d_in[3];
    const float* b2 = (const float*)d_in[4];
    float* out = (float*)d_out;

    u16* wB = (u16*)d_ws;                               // 110,592 B packed weights
    u16* h1 = (u16*)((char*)d_ws + 131072);

    pack_w2<<<27, 256, 0, stream>>>(w2, wB);

    const size_t per_batch = (size_t)H1_BATCH * 2;      // 1,728,000 B
    size_t avail = ws_size > 131072 ? ws_size - 131072 : 0;
    int bchunk = (int)(avail / per_batch);
    if (bchunk < 1)  bchunk = 1;
    if (bchunk > 64) bchunk = 64;

    for (int b0 = 0; b0 < 64; b0 += bchunk) {
        int bc = 64 - b0;
        if (bc > bchunk) bc = bchunk;
        conv1_relu<<<dim3(30, 5, bc), 256, 0, stream>>>(x, w1, b1, h1, b0);
        conv2_mfma<<<dim3(98 * bc), 256, 0, stream>>>(h1, wB, b2, out, b0);
    }
}

// Round 8
// 355.185 us; speedup vs baseline: 7.2629x; 1.0119x over previous
//
#include <hip/hip_runtime.h>
#include <cstdint>
#include <cstddef>

typedef __attribute__((ext_vector_type(8))) short bf16x8;
typedef __attribute__((ext_vector_type(4))) float f32x4;
typedef __attribute__((ext_vector_type(4))) unsigned int u32x4;
typedef unsigned short u16;

#define H1_ROW_B   1920                 /* packed row: 30x * 32ci * 2B     */
#define H1_BATCH   (30 * 30 * 960)      /* elems per batch (864000)        */
#define LDS_STRIDE 1184                 /* 1152 + 32: bank phasing         */
#define OUT_CSTR   21952                /* 28*28*28                        */

__device__ __forceinline__ u16 f2bf(float f) {
    union { float f; unsigned u; } v; v.f = f;
    unsigned r = v.u + 0x7FFF + ((v.u >> 16) & 1);   // RNE
    return (u16)(r >> 16);
}

__device__ __forceinline__ void fma4(float4& a, float s, const float4& w) {
    a.x = fmaf(s, w.x, a.x);
    a.y = fmaf(s, w.y, a.y);
    a.z = fmaf(s, w.z, a.z);
    a.w = fmaf(s, w.w, a.w);
}

// ---------------- conv1 + bias + relu -> bf16 h1 [bl][z][y][30x][32ci] ----
__global__ __launch_bounds__(256) void conv1_relu(
    const float* __restrict__ x, const float* __restrict__ w1,
    const float* __restrict__ b1, u16* __restrict__ h1, int b0)
{
    __shared__ float wl[27 * 32 + 32];

    const int z   = blockIdx.x;        // 0..29
    const int yt  = blockIdx.y;        // 0..4
    const int bl  = blockIdx.z;
    const int b   = b0 + bl;
    const int tid = threadIdx.x;

    for (int i = tid; i < 27 * 32; i += 256) wl[i] = w1[i];
    if (tid < 32) wl[27 * 32 + tid] = b1[tid];
    __syncthreads();

    const int c4    = tid & 7;
    const int xslot = tid >> 3;

    const float4 bias = *reinterpret_cast<const float4*>(&wl[27 * 32 + c4 * 4]);
    const float* xb  = x + (size_t)b * 32768;
    u16*         h1b = h1 + (size_t)bl * H1_BATCH;

#pragma unroll 1
    for (int j = 0; j < 6; ++j) {
        const int s = xslot + 32 * j;       // over 180 sites
        if (s >= 180) break;
        const int yy = s / 30;
        const int xx = s - yy * 30;
        const int y  = yt * 6 + yy;

        float4 acc = bias;
#pragma unroll
        for (int kd = 0; kd < 3; ++kd) {
#pragma unroll
            for (int kh = 0; kh < 3; ++kh) {
                const float* row = xb + ((size_t)(z + kd) * 32 + (y + kh)) * 32 + xx;
                const float a0 = row[0], a1 = row[1], a2 = row[2];
                const int t = (kd * 3 + kh) * 3;
                const float4 w0  = *reinterpret_cast<const float4*>(&wl[(t + 0) * 32 + c4 * 4]);
                const float4 w1v = *reinterpret_cast<const float4*>(&wl[(t + 1) * 32 + c4 * 4]);
                const float4 w2v = *reinterpret_cast<const float4*>(&wl[(t + 2) * 32 + c4 * 4]);
                fma4(acc, a0, w0);
                fma4(acc, a1, w1v);
                fma4(acc, a2, w2v);
            }
        }
        ushort4 st;
        st.x = f2bf(fmaxf(acc.x, 0.f));
        st.y = f2bf(fmaxf(acc.y, 0.f));
        st.z = f2bf(fmaxf(acc.z, 0.f));
        st.w = f2bf(fmaxf(acc.w, 0.f));
        *reinterpret_cast<ushort4*>(
            h1b + ((size_t)(z * 30 + y) * 30 + xx) * 32 + c4 * 4) = st;
    }
}

// ---------------- pack w2 fp32 DHWIO -> bf16 B-fragments ------------------
// wB[((tap*4 + nt)*64 + lane)*8 + j] = bf16(w2[tap][(lane>>4)*8 + j][nt*16 + (lane&15)])
__global__ __launch_bounds__(256) void pack_w2(
    const float* __restrict__ w2, u16* __restrict__ wB)
{
    const int tap = blockIdx.x;      // 0..26
    const int tid = threadIdx.x;
    const int nt = tid >> 6;
    const int l  = tid & 63;
    const int r = l & 15, q = l >> 4;
    u16* dst = wB + ((size_t)(tap * 4 + nt) * 64 + l) * 8;
#pragma unroll
    for (int j = 0; j < 8; ++j)
        dst[j] = f2bf(w2[(size_t)(tap * 32 + q * 8 + j) * 64 + nt * 16 + r]);
}

// ---------------- conv2 implicit-GEMM MFMA, x-split tiles -----------------
// Grid 98*bc blocks (XCD-swizzled when %8==0). Per batch: 98 = 7yg*7zt*2xh.
// Block: 4 waves; wave wv -> z=z0+wv, y0..y0+3.
//   xh=0: out x 0..15 (4 m-tiles, XIN=0);  xh=1: out x 16..27 (3, XIN=12).
// A in LDS: 36 rows x 1152 B (18 x-pos), stride 1184 (bank phasing).
// B 1-tap-ahead in regs via inline-asm global_load_dwordx4 + vmcnt(4).
// NEW (r8): 2-stage A-fragment register pipeline — tap t+1's ds_reads are
// issued before tap t's MFMA cluster, hiding the ~120cy LDS latency.
template<int NMT, int XIN, int XOUT>
__device__ __forceinline__ void conv2_body(
    const unsigned char* smem, const char* wBl,
    const float* __restrict__ b2, float* __restrict__ out,
    int b, int y0, int z0, int wv, int l)
{
    const int r = l & 15, q = l >> 4;
    const int yl = r >> 2, xg = r & 3;

    f32x4 acc[NMT][4];
#pragma unroll
    for (int nt = 0; nt < 4; ++nt) {
        const float bv = b2[nt * 16 + r];
        const f32x4 bi = {bv, bv, bv, bv};
#pragma unroll
        for (int mt = 0; mt < NMT; ++mt) acc[mt][nt] = bi;
    }

    // per-lane A base; per tap add ((kd*6+kh)*LDS_STRIDE + kw*64) [const]
    const unsigned char* aBase =
        smem + (wv * 6 + yl) * LDS_STRIDE + (XOUT - XIN + xg) * 64 + q * 16;

    u32x4 Bs[2][4];
#define B_LOAD(slot, t)                                                        \
    { const char* p_ = wBl + (size_t)(t) * 4096;                               \
      asm volatile("global_load_dwordx4 %0, %4, off\n\t"                       \
                   "global_load_dwordx4 %1, %4, off offset:1024\n\t"           \
                   "global_load_dwordx4 %2, %4, off offset:2048\n\t"           \
                   "global_load_dwordx4 %3, %4, off offset:3072"               \
                   : "=&v"(Bs[slot][0]), "=&v"(Bs[slot][1]),                   \
                     "=&v"(Bs[slot][2]), "=&v"(Bs[slot][3])                    \
                   : "v"(p_)); }

    // tap-0 B load (staging loads already drained by caller's barrier, so
    // vmcnt counts below are exact: only our B loads are outstanding)
    B_LOAD(0, 0)

    // ---- A-fragment 2-stage register pipeline: preload tap 0 ----
    bf16x8 Ar[2][NMT];
#pragma unroll
    for (int mt = 0; mt < NMT; ++mt)
        Ar[0][mt] = *reinterpret_cast<const bf16x8*>(aBase + mt * 256);

#pragma unroll
    for (int tap = 0; tap < 27; ++tap) {
        const int cur = tap & 1, nxt = cur ^ 1;

        if (tap < 26) {
            B_LOAD(nxt, tap + 1)
            // prefetch A(t+1) into the alternate buffer (consumed next tap;
            // compiler emits counted lgkmcnt with the MFMA cluster between)
            const int t1  = tap + 1;
            const int kd1 = t1 / 9;
            const int kh1 = (t1 - kd1 * 9) / 3;
            const int kw1 = t1 - kd1 * 9 - kh1 * 3;
            const unsigned char* apn =
                aBase + (kd1 * 6 + kh1) * LDS_STRIDE + kw1 * 64;
#pragma unroll
            for (int mt = 0; mt < NMT; ++mt)
                Ar[nxt][mt] = *reinterpret_cast<const bf16x8*>(apn + mt * 256);
        }

        // after wait: only tap t+1's 4 B loads may remain in flight
        if (tap < 26) asm volatile("s_waitcnt vmcnt(4)");
        else          asm volatile("s_waitcnt vmcnt(0)");

        asm volatile("" : "+v"(Bs[cur][0]), "+v"(Bs[cur][1]),
                          "+v"(Bs[cur][2]), "+v"(Bs[cur][3]));
        const bf16x8 B0 = __builtin_bit_cast(bf16x8, Bs[cur][0]);
        const bf16x8 B1 = __builtin_bit_cast(bf16x8, Bs[cur][1]);
        const bf16x8 B2 = __builtin_bit_cast(bf16x8, Bs[cur][2]);
        const bf16x8 B3 = __builtin_bit_cast(bf16x8, Bs[cur][3]);

        __builtin_amdgcn_s_setprio(1);
#pragma unroll
        for (int mt = 0; mt < NMT; ++mt) {
            const bf16x8 a = Ar[cur][mt];
            acc[mt][0] = __builtin_amdgcn_mfma_f32_16x16x32_bf16(a, B0, acc[mt][0], 0, 0, 0);
            acc[mt][1] = __builtin_amdgcn_mfma_f32_16x16x32_bf16(a, B1, acc[mt][1], 0, 0, 0);
            acc[mt][2] = __builtin_amdgcn_mfma_f32_16x16x32_bf16(a, B2, acc[mt][2], 0, 0, 0);
            acc[mt][3] = __builtin_amdgcn_mfma_f32_16x16x32_bf16(a, B3, acc[mt][3], 0, 0, 0);
        }
        __builtin_amdgcn_s_setprio(0);
    }
#undef B_LOAD

    // epilogue: lane (r,q): co = nt*16+r, y = y0+q, x = XOUT+mt*4 (+j contig)
    const int z = z0 + wv;
    float* ob = out + ((size_t)b * 64 + r) * OUT_CSTR
                    + (size_t)z * 784 + (size_t)(y0 + q) * 28 + XOUT;
#pragma unroll
    for (int mt = 0; mt < NMT; ++mt) {
#pragma unroll
        for (int nt = 0; nt < 4; ++nt) {
            const f32x4 v = acc[mt][nt];
            float4 st;
            st.x = fmaxf(v.x, 0.f);
            st.y = fmaxf(v.y, 0.f);
            st.z = fmaxf(v.z, 0.f);
            st.w = fmaxf(v.w, 0.f);
            *reinterpret_cast<float4*>(ob + (size_t)nt * 16 * OUT_CSTR + mt * 4) = st;
        }
    }
}

__global__ __launch_bounds__(256, 3) void conv2_mfma(
    const u16* __restrict__ h1, const u16* __restrict__ wB,
    const float* __restrict__ b2, float* __restrict__ out, int b0)
{
    __shared__ __align__(16) unsigned char smem[36 * LDS_STRIDE];  // 42624 B

    const int g   = gridDim.x;
    const int bid = blockIdx.x;
    const int lb  = (g % 8 == 0) ? ((bid & 7) * (g >> 3) + (bid >> 3)) : bid;

    const int t   = lb % 98;
    const int bl  = lb / 98;
    const int xh  = t / 49;
    const int u   = t % 49;
    const int yg  = u % 7;
    const int zt  = u / 7;

    const int b  = b0 + bl;
    const int y0 = yg * 4, z0 = zt * 4;
    const int tid = threadIdx.x;
    const int wv  = tid >> 6;
    const int l   = tid & 63;

    const char* wBl = (const char*)wB + l * 16;

    // ---- stage A: 36 rows x 1152 B from x-offset XIN, stride 1184 ----
    const int xin = xh ? 12 : 0;
    {
        const char* gbase = (const char*)(h1 + (size_t)bl * H1_BATCH) + xin * 64;
        for (int c = wv; c < 72; c += 4) {           // wave-uniform chunks
            const int rid = c >> 1, half = c & 1;    // two overlapped 1KB chunks
            const int zz = rid / 6, yy = rid - zz * 6;
            const char* src = gbase
                + (size_t)((z0 + zz) * 30 + (y0 + yy)) * H1_ROW_B
                + half * 128 + l * 16;
            unsigned char* dst = smem + rid * LDS_STRIDE + half * 128 + l * 16;
            __builtin_amdgcn_global_load_lds(
                (const __attribute__((address_space(1))) void*)src,
                (__attribute__((address_space(3))) void*)dst, 16, 0, 0);
        }
    }
    __syncthreads();   // drains staging (vmcnt(0)) + publishes LDS

    if (xh == 0)
        conv2_body<4, 0, 0>(smem, wBl, b2, out, b, y0, z0, wv, l);
    else
        conv2_body<3, 12, 16>(smem, wBl, b2, out, b, y0, z0, wv, l);
}

extern "C" void kernel_launch(void* const* d_in, const int* in_sizes, int n_in,
                              void* d_out, int out_size, void* d_ws, size_t ws_size,
                              hipStream_t stream)
{
    const float* x  = (const float*)d_in[0];
    const float* w1 = (const float*)d_in[1];
    const float* b1 = (const float*)d_in[2];
    const float* w2 = (const float*)d_in[3];
    const float* b2 = (const float*)d_in[4];
    float* out = (float*)d_out;

    u16* wB = (u16*)d_ws;                               // 110,592 B packed weights
    u16* h1 = (u16*)((char*)d_ws + 131072);

    pack_w2<<<27, 256, 0, stream>>>(w2, wB);

    const size_t per_batch = (size_t)H1_BATCH * 2;      // 1,728,000 B
    size_t avail = ws_size > 131072 ? ws_size - 131072 : 0;
    int bchunk = (int)(avail / per_batch);
    if (bchunk < 1)  bchunk = 1;
    if (bchunk > 64) bchunk = 64;

    for (int b0 = 0; b0 < 64; b0 += bchunk) {
        int bc = 64 - b0;
        if (bc > bchunk) bc = bchunk;
        conv1_relu<<<dim3(30, 5, bc), 256, 0, stream>>>(x, w1, b1, h1, b0);
        conv2_mfma<<<dim3(98 * bc), 256, 0, stream>>>(h1, wB, b2, out, b0);
    }
}

// Round 9
// 270.185 us; speedup vs baseline: 9.5478x; 1.3146x over previous
//
#include <hip/hip_runtime.h>
#include <cstdint>
#include <cstddef>

typedef __attribute__((ext_vector_type(8))) short bf16x8;
typedef __attribute__((ext_vector_type(4))) float f32x4;
typedef __attribute__((ext_vector_type(4))) unsigned int u32x4;
typedef unsigned short u16;

#define H1_ROW_B   1920                 /* packed row: 30x * 32ci * 2B     */
#define H1_BATCH   (30 * 30 * 960)      /* elems per batch (864000)        */
#define LDS_STRIDE 1952                 /* 1920 + 32: 488 dw = 8-bank row shift */
#define OUT_CSTR   21952                /* 28*28*28                        */

__device__ __forceinline__ u16 f2bf(float f) {
    union { float f; unsigned u; } v; v.f = f;
    unsigned r = v.u + 0x7FFF + ((v.u >> 16) & 1);   // RNE
    return (u16)(r >> 16);
}

__device__ __forceinline__ void fma4(float4& a, float s, const float4& w) {
    a.x = fmaf(s, w.x, a.x);
    a.y = fmaf(s, w.y, a.y);
    a.z = fmaf(s, w.z, a.z);
    a.w = fmaf(s, w.w, a.w);
}

// ---------------- conv1 + bias + relu -> bf16 h1 [bl][z][y][30x][32ci] ----
__global__ __launch_bounds__(256) void conv1_relu(
    const float* __restrict__ x, const float* __restrict__ w1,
    const float* __restrict__ b1, u16* __restrict__ h1, int b0)
{
    __shared__ float wl[27 * 32 + 32];

    const int z   = blockIdx.x;        // 0..29
    const int yt  = blockIdx.y;        // 0..4
    const int bl  = blockIdx.z;
    const int b   = b0 + bl;
    const int tid = threadIdx.x;

    for (int i = tid; i < 27 * 32; i += 256) wl[i] = w1[i];
    if (tid < 32) wl[27 * 32 + tid] = b1[tid];
    __syncthreads();

    const int c4    = tid & 7;
    const int xslot = tid >> 3;

    const float4 bias = *reinterpret_cast<const float4*>(&wl[27 * 32 + c4 * 4]);
    const float* xb  = x + (size_t)b * 32768;
    u16*         h1b = h1 + (size_t)bl * H1_BATCH;

#pragma unroll 1
    for (int j = 0; j < 6; ++j) {
        const int s = xslot + 32 * j;       // over 180 sites
        if (s >= 180) break;
        const int yy = s / 30;
        const int xx = s - yy * 30;
        const int y  = yt * 6 + yy;

        float4 acc = bias;
#pragma unroll
        for (int kd = 0; kd < 3; ++kd) {
#pragma unroll
            for (int kh = 0; kh < 3; ++kh) {
                const float* row = xb + ((size_t)(z + kd) * 32 + (y + kh)) * 32 + xx;
                const float a0 = row[0], a1 = row[1], a2 = row[2];
                const int t = (kd * 3 + kh) * 3;
                const float4 w0  = *reinterpret_cast<const float4*>(&wl[(t + 0) * 32 + c4 * 4]);
                const float4 w1v = *reinterpret_cast<const float4*>(&wl[(t + 1) * 32 + c4 * 4]);
                const float4 w2v = *reinterpret_cast<const float4*>(&wl[(t + 2) * 32 + c4 * 4]);
                fma4(acc, a0, w0);
                fma4(acc, a1, w1v);
                fma4(acc, a2, w2v);
            }
        }
        ushort4 st;
        st.x = f2bf(fmaxf(acc.x, 0.f));
        st.y = f2bf(fmaxf(acc.y, 0.f));
        st.z = f2bf(fmaxf(acc.z, 0.f));
        st.w = f2bf(fmaxf(acc.w, 0.f));
        *reinterpret_cast<ushort4*>(
            h1b + ((size_t)(z * 30 + y) * 30 + xx) * 32 + c4 * 4) = st;
    }
}

// ---------------- pack w2 fp32 DHWIO -> bf16 B-fragments ------------------
// wB[((tap*4 + nt)*64 + lane)*8 + j] = bf16(w2[tap][(lane>>4)*8 + j][nt*16 + (lane&15)])
__global__ __launch_bounds__(256) void pack_w2(
    const float* __restrict__ w2, u16* __restrict__ wB)
{
    const int tap = blockIdx.x;      // 0..26
    const int tid = threadIdx.x;
    const int nt = tid >> 6;
    const int l  = tid & 63;
    const int r = l & 15, q = l >> 4;
    u16* dst = wB + ((size_t)(tap * 4 + nt) * 64 + l) * 8;
#pragma unroll
    for (int j = 0; j < 8; ++j)
        dst[j] = f2bf(w2[(size_t)(tap * 32 + q * 8 + j) * 64 + nt * 16 + r]);
}

// ---------------- conv2 implicit-GEMM MFMA, 8-wave N-split ----------------
// Grid 49*bc x 512 thr (XCD-swizzled when %8==0). Block: 4z x 4y x 28x.
// 8 waves: wave wv -> z-plane zw=wv>>1, N-half nh=wv&1 (co nh*32..+31).
// Per wave: 7 m-tiles x 2 n-frags, K=27 taps x 32ci.
// A in LDS: 36 rows x 1920 B, stride 1952 (8-bank shift; verified 0-conflict
// pattern from r6). B from global: 2 KB/wave/tap, 1-ahead, counted vmcnt(2).
// 2 blocks/CU (140.5 KB LDS) x 8 waves = 4 waves/SIMD target occupancy.
__global__ __launch_bounds__(512, 4) void conv2_mfma(
    const u16* __restrict__ h1, const u16* __restrict__ wB,
    const float* __restrict__ b2, float* __restrict__ out, int b0)
{
    __shared__ __align__(16) unsigned char smem[36 * LDS_STRIDE];  // 70272 B

    const int g   = gridDim.x;
    const int bid = blockIdx.x;
    const int lb  = (g % 8 == 0) ? ((bid & 7) * (g >> 3) + (bid >> 3)) : bid;

    const int t0  = lb % 49;
    const int bl  = lb / 49;
    const int yg  = t0 % 7;
    const int zt  = t0 / 7;

    const int b  = b0 + bl;
    const int y0 = yg * 4, z0 = zt * 4;
    const int tid = threadIdx.x;
    const int wv  = tid >> 6;       // 0..7
    const int l   = tid & 63;
    const int zw  = wv >> 1;        // wave z offset 0..3
    const int nh  = wv & 1;         // wave N half
    const int r = l & 15, q = l >> 4;
    const int yl = r >> 2, xg = r & 3;

    const char* wBl = (const char*)wB + nh * 2048 + l * 16;

    // ---- stage A: 36 rows x 1920 B, chunks at 0 and 896 (128 B overlap) --
    {
        const char* gbase = (const char*)(h1 + (size_t)bl * H1_BATCH);
        for (int c = wv; c < 72; c += 8) {           // wave-uniform chunks
            const int rid = c >> 1, half = c & 1;
            const int zz = rid / 6, yy = rid - zz * 6;
            const char* src = gbase
                + (size_t)((z0 + zz) * 30 + (y0 + yy)) * H1_ROW_B
                + half * 896 + l * 16;
            unsigned char* dst = smem + rid * LDS_STRIDE + half * 896 + l * 16;
            __builtin_amdgcn_global_load_lds(
                (const __attribute__((address_space(1))) void*)src,
                (__attribute__((address_space(3))) void*)dst, 16, 0, 0);
        }
    }
    __syncthreads();   // drains staging (vmcnt(0)) + publishes LDS

    // ---- accumulators init with bias (co = nh*32 + nt*16 + r) ----
    f32x4 acc[7][2];
    {
        const float bv0 = b2[nh * 32 + r];
        const float bv1 = b2[nh * 32 + 16 + r];
#pragma unroll
        for (int mt = 0; mt < 7; ++mt) {
            acc[mt][0] = (f32x4){bv0, bv0, bv0, bv0};
            acc[mt][1] = (f32x4){bv1, bv1, bv1, bv1};
        }
    }

    // per-lane A base: row (zw+kd)*6 + (yl+kh), x = mt*4 + xg + kw, K-quarter q
    const unsigned char* aBase =
        smem + (zw * 6 + yl) * LDS_STRIDE + xg * 64 + q * 16;

    u32x4 Bs[2][2];
#define B_LOAD(slot, t)                                                        \
    { const char* p_ = wBl + (size_t)(t) * 4096;                               \
      asm volatile("global_load_dwordx4 %0, %2, off\n\t"                       \
                   "global_load_dwordx4 %1, %2, off offset:1024"               \
                   : "=&v"(Bs[slot][0]), "=&v"(Bs[slot][1]) : "v"(p_)); }

    // tap-0 B load (staging already drained -> vmcnt counts below are exact)
    B_LOAD(0, 0)

    // ---- barrier-free K-loop over 27 taps, fully unrolled ----
#pragma unroll
    for (int tap = 0; tap < 27; ++tap) {
        const int cur = tap & 1;

        if (tap < 26) B_LOAD(cur ^ 1, tap + 1)

        // after wait: only tap t+1's 2 loads may remain in flight
        if (tap < 26) asm volatile("s_waitcnt vmcnt(2)");
        else          asm volatile("s_waitcnt vmcnt(0)");

        asm volatile("" : "+v"(Bs[cur][0]), "+v"(Bs[cur][1]));
        const bf16x8 B0 = __builtin_bit_cast(bf16x8, Bs[cur][0]);
        const bf16x8 B1 = __builtin_bit_cast(bf16x8, Bs[cur][1]);

        const int kd = tap / 9;
        const int kh = (tap - kd * 9) / 3;
        const int kw = tap - kd * 9 - kh * 3;
        const unsigned char* ap = aBase + (kd * 6 + kh) * LDS_STRIDE + kw * 64;

        __builtin_amdgcn_s_setprio(1);
#pragma unroll
        for (int mt = 0; mt < 7; ++mt) {
            const bf16x8 a = *reinterpret_cast<const bf16x8*>(ap + mt * 256);
            acc[mt][0] = __builtin_amdgcn_mfma_f32_16x16x32_bf16(a, B0, acc[mt][0], 0, 0, 0);
            acc[mt][1] = __builtin_amdgcn_mfma_f32_16x16x32_bf16(a, B1, acc[mt][1], 0, 0, 0);
        }
        __builtin_amdgcn_s_setprio(0);
    }
#undef B_LOAD

    // ---- epilogue: lane (r,q): co = nh*32+nt*16+r, y = y0+q, x = mt*4 (+j)
    const int z = z0 + zw;
    float* ob = out + ((size_t)b * 64 + nh * 32 + r) * OUT_CSTR
                    + (size_t)z * 784 + (size_t)(y0 + q) * 28;
#pragma unroll
    for (int mt = 0; mt < 7; ++mt) {
#pragma unroll
        for (int nt = 0; nt < 2; ++nt) {
            const f32x4 v = acc[mt][nt];
            float4 st;
            st.x = fmaxf(v.x, 0.f);
            st.y = fmaxf(v.y, 0.f);
            st.z = fmaxf(v.z, 0.f);
            st.w = fmaxf(v.w, 0.f);
            *reinterpret_cast<float4*>(ob + (size_t)nt * 16 * OUT_CSTR + mt * 4) = st;
        }
    }
}

extern "C" void kernel_launch(void* const* d_in, const int* in_sizes, int n_in,
                              void* d_out, int out_size, void* d_ws, size_t ws_size,
                              hipStream_t stream)
{
    const float* x  = (const float*)d_in[0];
    const float* w1 = (const float*)d_in[1];
    const float* b1 = (const float*)d_in[2];
    const float* w2 = (const float*)d_in[3];
    const float* b2 = (const float*)d_in[4];
    float* out = (float*)d_out;

    u16* wB = (u16*)d_ws;                               // 110,592 B packed weights
    u16* h1 = (u16*)((char*)d_ws + 131072);

    pack_w2<<<27, 256, 0, stream>>>(w2, wB);

    const size_t per_batch = (size_t)H1_BATCH * 2;      // 1,728,000 B
    size_t avail = ws_size > 131072 ? ws_size - 131072 : 0;
    int bchunk = (int)(avail / per_batch);
    if (bchunk < 1)  bchunk = 1;
    if (bchunk > 64) bchunk = 64;

    for (int b0 = 0; b0 < 64; b0 += bchunk) {
        int bc = 64 - b0;
        if (bc > bchunk) bc = bchunk;
        conv1_relu<<<dim3(30, 5, bc), 256, 0, stream>>>(x, w1, b1, h1, b0);
        conv2_mfma<<<dim3(49 * bc), 512, 0, stream>>>(h1, wB, b2, out, b0);
    }
}